// Round 7
// baseline (195.570 us; speedup 1.0000x reference)
//
#include <hip/hip_runtime.h>
#include <cstdint>
#include <cstddef>

// ---------------------------------------------------------------------------
// LSTM cell, fully fused GEMM+epilogue:
//   gates = [x|h] (2048x4096) · [W_ih|W_hh]^T (8192x4096) + b  -> LSTM math
// R7: W is read as fp32 DIRECTLY by the GEMM (reg-staged, v_cvt_pk_bf16_f32,
// ds_write into the swizzled LDS layout) — the 35 µs W-cvt pass is gone.
// A ([x|h] bf16 concat) still packed by a small cvt kernel + global_load_lds.
// ---------------------------------------------------------------------------

typedef __attribute__((ext_vector_type(8))) short bf16x8;
typedef __attribute__((ext_vector_type(4))) float f32x4;

#define GLD_AS1 const __attribute__((address_space(1))) void
#define GLD_AS3 __attribute__((address_space(3))) void

__device__ __forceinline__ void gload_lds16(const void* g, void* l) {
  __builtin_amdgcn_global_load_lds((GLD_AS1*)g, (GLD_AS3*)l, 16, 0, 0);
}

__device__ __forceinline__ unsigned short f2bf(float f) {
  unsigned int u = __float_as_uint(f);
  unsigned int r = 0x7FFFu + ((u >> 16) & 1u);
  return (unsigned short)((u + r) >> 16);
}

__device__ __forceinline__ void barrier_f() {
  asm volatile("" ::: "memory");
  __builtin_amdgcn_s_barrier();
  asm volatile("" ::: "memory");
}

__device__ __forceinline__ uint4 pk8(float4 a, float4 b) {
  uint4 d;
  asm("v_cvt_pk_bf16_f32 %0, %1, %2" : "=v"(d.x) : "v"(a.x), "v"(a.y));
  asm("v_cvt_pk_bf16_f32 %0, %1, %2" : "=v"(d.y) : "v"(a.z), "v"(a.w));
  asm("v_cvt_pk_bf16_f32 %0, %1, %2" : "=v"(d.z) : "v"(b.x), "v"(b.y));
  asm("v_cvt_pk_bf16_f32 %0, %1, %2" : "=v"(d.w) : "v"(b.z), "v"(b.w));
  return d;
}

__device__ __forceinline__ float sigm(float x) { return 1.0f / (1.0f + __expf(-x)); }

// ---- pack A = [x|h]: fp32 (rows x 2048) -> bf16 (rows x 4096, col off) ----
__global__ __launch_bounds__(256) void cvt_A(const float* __restrict__ x,
                                             const float* __restrict__ h,
                                             unsigned short* __restrict__ Abf) {
  int bid = blockIdx.x;
  const float* src; int col_off; int base;
  if (bid < 4096) { src = x; col_off = 0;    base = bid; }
  else            { src = h; col_off = 2048; base = bid - 4096; }
  int i = base * 256 + threadIdx.x;
  int flat = i << 2;
  int r = flat >> 11;
  int c = flat & 2047;
  float4 v = *(const float4*)(src + flat);
  ushort4 o;
  o.x = f2bf(v.x); o.y = f2bf(v.y); o.z = f2bf(v.z); o.w = f2bf(v.w);
  *(ushort4*)(Abf + (((size_t)r) << 12) + col_off + c) = o;
}

// ---- fused 256² bf16 GEMM + LSTM epilogue ----------------------------------
// BM=256 M-rows, "BN=256" = 4 gates x 64 h-cols (permuted W rows), BK=64.
// LDS 128 KiB: lds[buf2][part4][128*64]; swizzle colbyte ^= (localrow&7)<<4.
// A: global_load_lds from pre-swizzled bf16 source (SA = 4 gloads/tile).
// B: reg-staged fp32 from W_ih/W_hh directly (BL = 8 dwordx4/tile, one tile
//    early), packed to bf16 (pk8) and ds_written swizzled (BW = 4 b128/tile).
// Steady-state waits: vmcnt(4) before BW(t+1); lgkm(0)+vmcnt(12) at boundary.
__global__ __launch_bounds__(512, 2) void gemm_lstm(
    const unsigned short* __restrict__ A,   // [2048][4096] bf16 = [x|h]
    const float* __restrict__ Wih,          // [8192][2048] fp32
    const float* __restrict__ Whh,          // [8192][2048] fp32
    const float* __restrict__ b_ih, const float* __restrict__ b_hh,
    const float* __restrict__ C_prev,       // [2048][2048] fp32
    float* __restrict__ out)                // 6 x [2048][2048] fp32
{
  constexpr int K = 4096;
  constexpr int BK = 64;
  constexpr int NT = K / BK;                // 64 K-tiles (t<32: Wih, t>=32: Whh)
  __shared__ alignas(16) unsigned short lds[2][4][128 * 64];  // 128 KiB

  // XCD slab: xc owns 4 h-tiles x all 8 bm-tiles
  int b  = blockIdx.x;
  int xc = b & 7, ii = b >> 3;
  int bm = (ii & 7) * 256;
  int h0 = (xc * 4 + (ii >> 3)) * 64;

  int tid  = threadIdx.x;
  int lane = tid & 63;
  int w    = tid >> 6;        // 0..7
  int wm   = w >> 2;          // A-half
  int wn   = w & 3;           // B-part wn>>1, sub-row (wn&1)*64
  int l15  = lane & 15;
  int lq   = lane >> 4;
  int sr3  = lane >> 3;       // 0..7 row-in-chunk
  int l7   = lane & 7;

  // swizzled fragment col (elements) for kq=0,1
  int ce0 = ((lq * 16) ^ ((l15 & 7) << 4)) >> 1;
  int ce1 = ((64 + lq * 16) ^ ((l15 & 7) << 4)) >> 1;

  // staging geometry: wave w handles local rows 16w..16w+15 of each part;
  // pre-swizzled source col = ((l&7)^(l>>3))*8 elements
  int scol = (l7 ^ sr3) * 8;
  const unsigned short* gA = A + (size_t)(bm + 16 * w + sr3) * K + scol;
  // B source row (fp32 W): Wrow = (w&3)*2048 + h0 + 16*(w>>2) + 32*p + sr3 + 8*i
  int bWrow = (w & 3) * 2048 + h0 + 16 * (w >> 2) + sr3;

  f32x4 acc[8][4] = {};
  float4 bl[8];               // B stage regs: [p*4 + i*2 + half]

  auto stageA = [&](int t, int hh) {   // 2 gloads each; SA = hh 0..1 -> 4
    unsigned short* l0 = &lds[t & 1][hh][w * 1024];
    const unsigned short* g = gA + (size_t)hh * 128 * K + t * BK;
    gload_lds16(g, l0);
    gload_lds16(g + (size_t)8 * K, l0 + 512);
  };
  auto loadB = [&](int tt) {           // 8 dwordx4 into bl
    const float* Wsel = (tt < 32) ? Wih : Whh;
    const float* gw = Wsel + (size_t)bWrow * 2048 + (tt & 31) * BK + scol;
#pragma unroll
    for (int p = 0; p < 2; ++p)
#pragma unroll
      for (int i = 0; i < 2; ++i) {
        const float* g = gw + (size_t)(32 * p + 8 * i) * 2048;
        bl[p * 4 + i * 2 + 0] = *(const float4*)(g);
        bl[p * 4 + i * 2 + 1] = *(const float4*)(g + 4);
      }
  };
  auto writeB = [&](int t) {           // pack + 4 ds_write_b128
#pragma unroll
    for (int p = 0; p < 2; ++p)
#pragma unroll
      for (int i = 0; i < 2; ++i) {
        uint4 d = pk8(bl[p * 4 + i * 2 + 0], bl[p * 4 + i * 2 + 1]);
        *(uint4*)&lds[t & 1][2 + p][(16 * w + 8 * i + sr3) * 64 + l7 * 8] = d;
      }
  };

  // ---- prologue: establish {tile0,1 staged; BL(1) in regs pending BW in t=0}
  loadB(0);
  asm volatile("" ::: "memory");
  stageA(0, 0); stageA(0, 1);
  asm volatile("" ::: "memory");
  asm volatile("s_waitcnt vmcnt(4)" ::: "memory");    // BL(0) landed
  writeB(0);
  loadB(1);
  asm volatile("" ::: "memory");
  stageA(1, 0); stageA(1, 1);
  asm volatile("" ::: "memory");
  asm volatile("s_waitcnt vmcnt(12)" ::: "memory");   // SA(0) landed
  asm volatile("s_waitcnt lgkmcnt(0)" ::: "memory");  // BW(0) visible
  barrier_f();

  bf16x8 af[4][2], bf01[2][2], bf23[2][2];

  for (int t = 0; t < NT; ++t) {
    const unsigned short* Ab = lds[t & 1][wm];
    const unsigned short* Bb = lds[t & 1][2 + (wn >> 1)];
    int brow = (wn & 1) * 64;

    // s1: reads A m0-3 (8) + B n0-3 (8)
#pragma unroll
    for (int mt = 0; mt < 4; ++mt) {
      af[mt][0] = *(const bf16x8*)&Ab[(mt * 16 + l15) * 64 + ce0];
      af[mt][1] = *(const bf16x8*)&Ab[(mt * 16 + l15) * 64 + ce1];
    }
#pragma unroll
    for (int nt = 0; nt < 2; ++nt) {
      bf01[nt][0] = *(const bf16x8*)&Bb[(brow + nt * 16 + l15) * 64 + ce0];
      bf01[nt][1] = *(const bf16x8*)&Bb[(brow + nt * 16 + l15) * 64 + ce1];
      bf23[nt][0] = *(const bf16x8*)&Bb[(brow + (2 + nt) * 16 + l15) * 64 + ce0];
      bf23[nt][1] = *(const bf16x8*)&Bb[(brow + (2 + nt) * 16 + l15) * 64 + ce1];
    }

    // s3: MFMA P0+P1: m0-3 x n0-3 (32)
    __builtin_amdgcn_s_setprio(1);
#pragma unroll
    for (int mt = 0; mt < 4; ++mt)
#pragma unroll
      for (int nt = 0; nt < 2; ++nt) {
        acc[mt][nt] = __builtin_amdgcn_mfma_f32_16x16x32_bf16(af[mt][0], bf01[nt][0], acc[mt][nt], 0, 0, 0);
        acc[mt][nt] = __builtin_amdgcn_mfma_f32_16x16x32_bf16(af[mt][1], bf01[nt][1], acc[mt][nt], 0, 0, 0);
        acc[mt][2 + nt] = __builtin_amdgcn_mfma_f32_16x16x32_bf16(af[mt][0], bf23[nt][0], acc[mt][2 + nt], 0, 0, 0);
        acc[mt][2 + nt] = __builtin_amdgcn_mfma_f32_16x16x32_bf16(af[mt][1], bf23[nt][1], acc[mt][2 + nt], 0, 0, 0);
      }
    __builtin_amdgcn_s_setprio(0);

    // s3.5: reads A m4-7 into af (anti-dep on P0/P1 keeps order; saves 32 VGPR)
#pragma unroll
    for (int mt = 0; mt < 4; ++mt) {
      af[mt][0] = *(const bf16x8*)&Ab[(64 + mt * 16 + l15) * 64 + ce0];
      af[mt][1] = *(const bf16x8*)&Ab[(64 + mt * 16 + l15) * 64 + ce1];
    }

    barrier_f();  // s4: all waves' B reads of lds[(t+1)&1].B long done (t-1)

    // s5: write B(t+1) into lds[(t+1)&1] parts 2/3
    if (t < NT - 1) {
      asm volatile("s_waitcnt vmcnt(4)" ::: "memory");  // BL(t+1) landed
      writeB(t + 1);
    }
    // s6.5: issue BL(t+2)
    if (t + 2 < NT) loadB(t + 2);
    asm volatile("" ::: "memory");

    // s7: MFMA P2: m4-7 x n2-3 (16)
    __builtin_amdgcn_s_setprio(1);
#pragma unroll
    for (int mt = 0; mt < 4; ++mt)
#pragma unroll
      for (int nt = 0; nt < 2; ++nt) {
        acc[4 + mt][2 + nt] = __builtin_amdgcn_mfma_f32_16x16x32_bf16(af[mt][0], bf23[nt][0], acc[4 + mt][2 + nt], 0, 0, 0);
        acc[4 + mt][2 + nt] = __builtin_amdgcn_mfma_f32_16x16x32_bf16(af[mt][1], bf23[nt][1], acc[4 + mt][2 + nt], 0, 0, 0);
      }
    __builtin_amdgcn_s_setprio(0);

    barrier_f();  // s8: all waves' A reads (s1+s3.5) done before here
    if (t + 2 < NT) { stageA(t + 2, 0); stageA(t + 2, 1); }

    // s9: MFMA P3: m4-7 x n0-1 (16)
    __builtin_amdgcn_s_setprio(1);
#pragma unroll
    for (int mt = 0; mt < 4; ++mt)
#pragma unroll
      for (int nt = 0; nt < 2; ++nt) {
        acc[4 + mt][nt] = __builtin_amdgcn_mfma_f32_16x16x32_bf16(af[mt][0], bf01[nt][0], acc[4 + mt][nt], 0, 0, 0);
        acc[4 + mt][nt] = __builtin_amdgcn_mfma_f32_16x16x32_bf16(af[mt][1], bf01[nt][1], acc[4 + mt][nt], 0, 0, 0);
      }
    __builtin_amdgcn_s_setprio(0);

    // s10: boundary — own BW writes drained + SA(t+1) landed, then sync
    if (t < NT - 1) {
      asm volatile("s_waitcnt lgkmcnt(0)" ::: "memory");
      if (t < NT - 2) asm volatile("s_waitcnt vmcnt(12)" ::: "memory");
      else            asm volatile("s_waitcnt vmcnt(0)" ::: "memory");
      barrier_f();
    }
  }

  // ---- fused LSTM epilogue ------------------------------------------------
  int hcol = h0 + wn * 16 + l15;
  float cb0 = b_ih[hcol]        + b_hh[hcol];
  float cb1 = b_ih[2048 + hcol] + b_hh[2048 + hcol];
  float cb2 = b_ih[4096 + hcol] + b_hh[4096 + hcol];
  float cb3 = b_ih[6144 + hcol] + b_hh[6144 + hcol];
  constexpr size_t SEC = (size_t)2048 * 2048;
#pragma unroll
  for (int mt = 0; mt < 8; ++mt) {
    int row0 = bm + wm * 128 + mt * 16 + lq * 4;
#pragma unroll
    for (int j = 0; j < 4; ++j) {
      size_t off = (size_t)(row0 + j) * 2048 + hcol;
      float I = sigm(acc[mt][0][j] + cb0);
      float F = sigm(acc[mt][1][j] + cb1);
      float G = tanhf(acc[mt][2][j] + cb2);
      float O = sigm(acc[mt][3][j] + cb3);
      float C = F * C_prev[off] + I * G;
      float H = O * tanhf(C);
      out[0 * SEC + off] = H;
      out[1 * SEC + off] = C;
      out[2 * SEC + off] = F;
      out[3 * SEC + off] = I;
      out[4 * SEC + off] = G;
      out[5 * SEC + off] = O;
    }
  }
}

// ---------------------------------------------------------------------------
extern "C" void kernel_launch(void* const* d_in, const int* in_sizes, int n_in,
                              void* d_out, int out_size, void* d_ws, size_t ws_size,
                              hipStream_t stream) {
  const float* x   = (const float*)d_in[0];
  const float* h   = (const float*)d_in[1];
  const float* Cp  = (const float*)d_in[2];
  const float* Wih = (const float*)d_in[3];
  const float* bih = (const float*)d_in[4];
  const float* Whh = (const float*)d_in[5];
  const float* bhh = (const float*)d_in[6];
  float* out = (float*)d_out;

  unsigned short* Abf = (unsigned short*)d_ws;   // 16 MiB: [x|h] bf16

  cvt_A<<<8192, 256, 0, stream>>>(x, h, Abf);
  gemm_lstm<<<256, 512, 0, stream>>>(Abf, Wih, Whh, bih, bhh, Cp, out);
}

// Round 8
// 189.904 us; speedup vs baseline: 1.0298x; 1.0298x over previous
//
#include <hip/hip_runtime.h>
#include <cstdint>
#include <cstddef>

// ---------------------------------------------------------------------------
// LSTM cell, fully fused GEMM+epilogue:
//   gates = [x|h] (2048x4096) · [W_ih|W_hh]^T (8192x4096) + b  -> LSTM math
// R8: W read as fp32 directly (reg-staged + cvt_pk + SWIZZLED ds_write —
// fixes R7's 8-way write-bank conflict), BL wait moved behind P2's MFMAs,
// boundary needs no vmcnt. A ([x|h] bf16) packed by cvt_A + global_load_lds.
// ---------------------------------------------------------------------------

typedef __attribute__((ext_vector_type(8))) short bf16x8;
typedef __attribute__((ext_vector_type(4))) float f32x4;

#define GLD_AS1 const __attribute__((address_space(1))) void
#define GLD_AS3 __attribute__((address_space(3))) void

__device__ __forceinline__ void gload_lds16(const void* g, void* l) {
  __builtin_amdgcn_global_load_lds((GLD_AS1*)g, (GLD_AS3*)l, 16, 0, 0);
}

__device__ __forceinline__ unsigned short f2bf(float f) {
  unsigned int u = __float_as_uint(f);
  unsigned int r = 0x7FFFu + ((u >> 16) & 1u);
  return (unsigned short)((u + r) >> 16);
}

__device__ __forceinline__ void barrier_f() {
  asm volatile("" ::: "memory");
  __builtin_amdgcn_s_barrier();
  asm volatile("" ::: "memory");
}

__device__ __forceinline__ uint4 pk8(float4 a, float4 b) {
  uint4 d;
  asm("v_cvt_pk_bf16_f32 %0, %1, %2" : "=v"(d.x) : "v"(a.x), "v"(a.y));
  asm("v_cvt_pk_bf16_f32 %0, %1, %2" : "=v"(d.y) : "v"(a.z), "v"(a.w));
  asm("v_cvt_pk_bf16_f32 %0, %1, %2" : "=v"(d.z) : "v"(b.x), "v"(b.y));
  asm("v_cvt_pk_bf16_f32 %0, %1, %2" : "=v"(d.w) : "v"(b.z), "v"(b.w));
  return d;
}

__device__ __forceinline__ float sigm(float x) { return 1.0f / (1.0f + __expf(-x)); }

// ---- pack A = [x|h]: fp32 (rows x 2048) -> bf16 (rows x 4096, col off) ----
__global__ __launch_bounds__(256) void cvt_A(const float* __restrict__ x,
                                             const float* __restrict__ h,
                                             unsigned short* __restrict__ Abf) {
  int bid = blockIdx.x;
  const float* src; int col_off; int base;
  if (bid < 4096) { src = x; col_off = 0;    base = bid; }
  else            { src = h; col_off = 2048; base = bid - 4096; }
  int i = base * 256 + threadIdx.x;
  int flat = i << 2;
  int r = flat >> 11;
  int c = flat & 2047;
  float4 v = *(const float4*)(src + flat);
  ushort4 o;
  o.x = f2bf(v.x); o.y = f2bf(v.y); o.z = f2bf(v.z); o.w = f2bf(v.w);
  *(ushort4*)(Abf + (((size_t)r) << 12) + col_off + c) = o;
}

// ---- fused 256² bf16 GEMM + LSTM epilogue ----------------------------------
// BM=256 M-rows, "BN=256" = 4 gates x 64 h-cols (permuted W rows), BK=64.
// LDS 128 KiB: lds[buf2][part4][128*64]; LDS[r][s16B] = global[r][s^(r&7)].
// A: global_load_lds, pre-swizzled global source, linear LDS dest.
// B: reg-staged fp32 (8 dwordx4, LINEAR global col), pk-cvt, ds_write at
//    SWIZZLED col (l7^sr3) — conflict-free writes, same read-side relation.
// Tile: BAR0 | 16 reads | P0P1(32 MFMA) | 8 reads | BAR1 | stageA(t+2) |
//       P2(16) | vmcnt(4) writeB(t+1) loadB(t+2) | P3(16) | lgkm0 BAR0
__global__ __launch_bounds__(512, 2) void gemm_lstm(
    const unsigned short* __restrict__ A,   // [2048][4096] bf16 = [x|h]
    const float* __restrict__ Wih,          // [8192][2048] fp32
    const float* __restrict__ Whh,          // [8192][2048] fp32
    const float* __restrict__ b_ih, const float* __restrict__ b_hh,
    const float* __restrict__ C_prev,       // [2048][2048] fp32
    float* __restrict__ out)                // 6 x [2048][2048] fp32
{
  constexpr int K = 4096;
  constexpr int BK = 64;
  constexpr int NT = K / BK;                // 64 K-tiles (t<32: Wih, t>=32: Whh)
  __shared__ alignas(16) unsigned short lds[2][4][128 * 64];  // 128 KiB

  int b  = blockIdx.x;
  int xc = b & 7, ii = b >> 3;
  int bm = (ii & 7) * 256;
  int h0 = (xc * 4 + (ii >> 3)) * 64;

  int tid  = threadIdx.x;
  int lane = tid & 63;
  int w    = tid >> 6;        // 0..7
  int wm   = w >> 2;          // A-half
  int wn   = w & 3;           // B-part wn>>1, sub-row (wn&1)*64
  int l15  = lane & 15;
  int lq   = lane >> 4;
  int sr3  = lane >> 3;       // 0..7 row-in-chunk
  int l7   = lane & 7;

  // swizzled fragment col (elements) for kq=0,1
  int ce0 = ((lq * 16) ^ ((l15 & 7) << 4)) >> 1;
  int ce1 = ((64 + lq * 16) ^ ((l15 & 7) << 4)) >> 1;

  // A staging: pre-swizzled global source col, linear LDS dest
  int scolA = (l7 ^ sr3) * 8;
  const unsigned short* gA = A + (size_t)(bm + 16 * w + sr3) * K + scolA;
  // B staging: LINEAR global col, swizzled LDS write col
  int bWrow = (w & 3) * 2048 + h0 + 16 * (w >> 2) + sr3;
  int bcolW = l7 * 8;                 // fp32 col (linear)
  int bcolL = (l7 ^ sr3) * 8;         // LDS bf16 col (swizzled)

  f32x4 acc[8][4] = {};
  float4 bl[8];                        // B stage regs

  auto stageA = [&](int t, int hh) {
    unsigned short* l0 = &lds[t & 1][hh][w * 1024];
    const unsigned short* g = gA + (size_t)hh * 128 * K + t * BK;
    gload_lds16(g, l0);
    gload_lds16(g + (size_t)8 * K, l0 + 512);
  };
  auto loadB = [&](int tt) {           // 8 dwordx4
    const float* Wsel = (tt < 32) ? Wih : Whh;
    const float* gw = Wsel + (size_t)bWrow * 2048 + (tt & 31) * BK + bcolW;
#pragma unroll
    for (int p = 0; p < 2; ++p)
#pragma unroll
      for (int i = 0; i < 2; ++i) {
        const float* g = gw + (size_t)(32 * p + 8 * i) * 2048;
        bl[p * 4 + i * 2 + 0] = *(const float4*)(g);
        bl[p * 4 + i * 2 + 1] = *(const float4*)(g + 4);
      }
  };
  auto writeB = [&](int t) {           // pack + 4 ds_write_b128 (swizzled col)
#pragma unroll
    for (int p = 0; p < 2; ++p)
#pragma unroll
      for (int i = 0; i < 2; ++i) {
        uint4 d = pk8(bl[p * 4 + i * 2 + 0], bl[p * 4 + i * 2 + 1]);
        *(uint4*)&lds[t & 1][2 + p][(16 * w + 8 * i + sr3) * 64 + bcolL] = d;
      }
  };

  // ---- prologue
  loadB(0);
  asm volatile("" ::: "memory");
  stageA(0, 0); stageA(0, 1);
  asm volatile("" ::: "memory");
  asm volatile("s_waitcnt vmcnt(4)" ::: "memory");    // BL(0) landed
  writeB(0);
  loadB(1);
  asm volatile("" ::: "memory");
  stageA(1, 0); stageA(1, 1);
  asm volatile("" ::: "memory");
  asm volatile("s_waitcnt vmcnt(12)" ::: "memory");   // SA(0) landed
  asm volatile("s_waitcnt lgkmcnt(0)" ::: "memory");  // BW(0) visible
  barrier_f();

  bf16x8 af[4][2], bf01[2][2], bf23[2][2];

  for (int t = 0; t < NT; ++t) {
    const unsigned short* Ab = lds[t & 1][wm];
    const unsigned short* Bb = lds[t & 1][2 + (wn >> 1)];
    int brow = (wn & 1) * 64;

    // s1: 16 reads (A m0-3, B n0-3)
#pragma unroll
    for (int mt = 0; mt < 4; ++mt) {
      af[mt][0] = *(const bf16x8*)&Ab[(mt * 16 + l15) * 64 + ce0];
      af[mt][1] = *(const bf16x8*)&Ab[(mt * 16 + l15) * 64 + ce1];
    }
#pragma unroll
    for (int nt = 0; nt < 2; ++nt) {
      bf01[nt][0] = *(const bf16x8*)&Bb[(brow + nt * 16 + l15) * 64 + ce0];
      bf01[nt][1] = *(const bf16x8*)&Bb[(brow + nt * 16 + l15) * 64 + ce1];
      bf23[nt][0] = *(const bf16x8*)&Bb[(brow + (2 + nt) * 16 + l15) * 64 + ce0];
      bf23[nt][1] = *(const bf16x8*)&Bb[(brow + (2 + nt) * 16 + l15) * 64 + ce1];
    }

    // P0+P1: m0-3 x n0-3 (32 MFMA)
    __builtin_amdgcn_s_setprio(1);
#pragma unroll
    for (int mt = 0; mt < 4; ++mt)
#pragma unroll
      for (int nt = 0; nt < 2; ++nt) {
        acc[mt][nt] = __builtin_amdgcn_mfma_f32_16x16x32_bf16(af[mt][0], bf01[nt][0], acc[mt][nt], 0, 0, 0);
        acc[mt][nt] = __builtin_amdgcn_mfma_f32_16x16x32_bf16(af[mt][1], bf01[nt][1], acc[mt][nt], 0, 0, 0);
        acc[mt][2 + nt] = __builtin_amdgcn_mfma_f32_16x16x32_bf16(af[mt][0], bf23[nt][0], acc[mt][2 + nt], 0, 0, 0);
        acc[mt][2 + nt] = __builtin_amdgcn_mfma_f32_16x16x32_bf16(af[mt][1], bf23[nt][1], acc[mt][2 + nt], 0, 0, 0);
      }
    __builtin_amdgcn_s_setprio(0);

    // s3.5: A m4-7 into af (anti-dep on P0/P1 keeps order)
#pragma unroll
    for (int mt = 0; mt < 4; ++mt) {
      af[mt][0] = *(const bf16x8*)&Ab[(64 + mt * 16 + l15) * 64 + ce0];
      af[mt][1] = *(const bf16x8*)&Ab[(64 + mt * 16 + l15) * 64 + ce1];
    }

    barrier_f();  // BAR1: all waves' A/B reads of this tile done

    if (t + 2 < NT) { stageA(t + 2, 0); stageA(t + 2, 1); }

    // P2: m4-7 x n2-3 (16 MFMA) — gives BL(t+1) extra landing time
    __builtin_amdgcn_s_setprio(1);
#pragma unroll
    for (int mt = 0; mt < 4; ++mt)
#pragma unroll
      for (int nt = 0; nt < 2; ++nt) {
        acc[4 + mt][2 + nt] = __builtin_amdgcn_mfma_f32_16x16x32_bf16(af[mt][0], bf23[nt][0], acc[4 + mt][2 + nt], 0, 0, 0);
        acc[4 + mt][2 + nt] = __builtin_amdgcn_mfma_f32_16x16x32_bf16(af[mt][1], bf23[nt][1], acc[4 + mt][2 + nt], 0, 0, 0);
      }
    __builtin_amdgcn_s_setprio(0);

    // drain BL(t+1) (+SA(t+1), older in queue), write B(t+1), issue BL(t+2)
    if (t + 1 < NT) {
      if (t + 2 < NT) asm volatile("s_waitcnt vmcnt(4)" ::: "memory");
      else            asm volatile("s_waitcnt vmcnt(0)" ::: "memory");
      writeB(t + 1);
      if (t + 2 < NT) loadB(t + 2);
      asm volatile("" ::: "memory");
    }

    // P3: m4-7 x n0-1 (16 MFMA)
    __builtin_amdgcn_s_setprio(1);
#pragma unroll
    for (int mt = 0; mt < 4; ++mt)
#pragma unroll
      for (int nt = 0; nt < 2; ++nt) {
        acc[4 + mt][nt] = __builtin_amdgcn_mfma_f32_16x16x32_bf16(af[mt][0], bf01[nt][0], acc[4 + mt][nt], 0, 0, 0);
        acc[4 + mt][nt] = __builtin_amdgcn_mfma_f32_16x16x32_bf16(af[mt][1], bf01[nt][1], acc[4 + mt][nt], 0, 0, 0);
      }
    __builtin_amdgcn_s_setprio(0);

    // boundary: own ds_writes visible; SA(t+1)/BW(t+1) certified by BAR
    if (t + 1 < NT) {
      asm volatile("s_waitcnt lgkmcnt(0)" ::: "memory");
      barrier_f();
    }
  }

  // ---- fused LSTM epilogue ------------------------------------------------
  int hcol = h0 + wn * 16 + l15;
  float cb0 = b_ih[hcol]        + b_hh[hcol];
  float cb1 = b_ih[2048 + hcol] + b_hh[2048 + hcol];
  float cb2 = b_ih[4096 + hcol] + b_hh[4096 + hcol];
  float cb3 = b_ih[6144 + hcol] + b_hh[6144 + hcol];
  constexpr size_t SEC = (size_t)2048 * 2048;
#pragma unroll
  for (int mt = 0; mt < 8; ++mt) {
    int row0 = bm + wm * 128 + mt * 16 + lq * 4;
#pragma unroll
    for (int j = 0; j < 4; ++j) {
      size_t off = (size_t)(row0 + j) * 2048 + hcol;
      float I = sigm(acc[mt][0][j] + cb0);
      float F = sigm(acc[mt][1][j] + cb1);
      float G = tanhf(acc[mt][2][j] + cb2);
      float O = sigm(acc[mt][3][j] + cb3);
      float C = F * C_prev[off] + I * G;
      float H = O * tanhf(C);
      out[0 * SEC + off] = H;
      out[1 * SEC + off] = C;
      out[2 * SEC + off] = F;
      out[3 * SEC + off] = I;
      out[4 * SEC + off] = G;
      out[5 * SEC + off] = O;
    }
  }
}

// ---------------------------------------------------------------------------
extern "C" void kernel_launch(void* const* d_in, const int* in_sizes, int n_in,
                              void* d_out, int out_size, void* d_ws, size_t ws_size,
                              hipStream_t stream) {
  const float* x   = (const float*)d_in[0];
  const float* h   = (const float*)d_in[1];
  const float* Cp  = (const float*)d_in[2];
  const float* Wih = (const float*)d_in[3];
  const float* bih = (const float*)d_in[4];
  const float* Whh = (const float*)d_in[5];
  const float* bhh = (const float*)d_in[6];
  float* out = (float*)d_out;

  unsigned short* Abf = (unsigned short*)d_ws;   // 16 MiB: [x|h] bf16

  cvt_A<<<8192, 256, 0, stream>>>(x, h, Abf);
  gemm_lstm<<<256, 512, 0, stream>>>(Abf, Wih, Whh, bih, bhh, Cp, out);
}